// Round 1
// baseline (159.287 us; speedup 1.0000x reference)
//
#include <hip/hip_runtime.h>

// out[b,k] = sum_l max_m dot(ctx[b,k,l,:], ent[b,k,m,:])
// ctx = context[:,:,0,:,:], ent = context[:,:,1,:,:]
// BATCH=8 TOP_K=64 MAX_LEN=256 EMB_DIM=768, fp32 in, fp32 out (8x64=512)

#define MAXLEN 256
#define EMB 768
#define BK 64
#define NSTEP (EMB / BK)   // 12
#define LSTRIDE 72         // 64 + 8 pad shorts -> 144 B row stride (9 x 16B granules, coprime with 8 banks-groups)

typedef __attribute__((ext_vector_type(4))) float f32x4;
typedef __attribute__((ext_vector_type(8))) short short8;
typedef __bf16 bf16x8 __attribute__((ext_vector_type(8)));

// round-to-nearest-even f32 -> bf16, packed pair (a -> low 16, b -> high 16)
__device__ inline unsigned int pack2bf(float a, float b) {
  unsigned int ua = __builtin_bit_cast(unsigned int, a);
  unsigned int ub = __builtin_bit_cast(unsigned int, b);
  ua = (ua + (0x7fffu + ((ua >> 16) & 1u))) >> 16;
  ub = (ub + (0x7fffu + ((ub >> 16) & 1u))) & 0xffff0000u;
  return ua | ub;
}

__device__ inline uint2 pack4bf(float4 v) {
  uint2 r;
  r.x = pack2bf(v.x, v.y);
  r.y = pack2bf(v.z, v.w);
  return r;
}

__global__ __launch_bounds__(512) void som_rowmax_kernel(
    const float* __restrict__ ctx_all, float* __restrict__ out) {
  __shared__ __align__(16) short lsA[2][MAXLEN][LSTRIDE];
  __shared__ __align__(16) short lsB[2][MAXLEN][LSTRIDE];
  __shared__ float red[8];

  const int t    = threadIdx.x;
  const int w    = t >> 6;      // wave 0..7
  const int lane = t & 63;
  const int qw   = lane >> 4;   // quarter-wave 0..3
  const int lr   = lane & 15;

  const size_t p = blockIdx.x;  // b*64 + k
  const float* ctx = ctx_all + p * (size_t)(2 * MAXLEN * EMB);
  const float* ent = ctx + (size_t)(MAXLEN * EMB);

  // staging geometry: 8 rounds x (32 rows x 16 float4-cols) covers 256x64 f32
  const int srow = t >> 4;         // 0..31
  const int scol = (t & 15) * 4;   // 0,4,...,60
  const float* gA = ctx + (size_t)srow * EMB + scol;
  const float* gB = ent + (size_t)srow * EMB + scol;

  f32x4 acc[2][16];
#pragma unroll
  for (int h = 0; h < 2; ++h)
#pragma unroll
    for (int mt = 0; mt < 16; ++mt)
      acc[h][mt] = (f32x4){0.f, 0.f, 0.f, 0.f};

  float4 ra[8], rb[8];

  // ---- prologue: stage step 0 into buffer 0 ----
#pragma unroll
  for (int r = 0; r < 8; ++r) {
    ra[r] = *(const float4*)(gA + (size_t)r * (32 * EMB));
    rb[r] = *(const float4*)(gB + (size_t)r * (32 * EMB));
  }
#pragma unroll
  for (int r = 0; r < 8; ++r) {
    const int row = r * 32 + srow;
    *(uint2*)&lsA[0][row][scol] = pack4bf(ra[r]);
    *(uint2*)&lsB[0][row][scol] = pack4bf(rb[r]);
  }
  __syncthreads();

  const int lt0 = 2 * w;
  const int lt1 = 2 * w + 1;

  for (int step = 0; step < NSTEP; ++step) {
    const int cur = step & 1;

    // issue next tile's global loads early (latency hides under MFMA)
    if (step + 1 < NSTEP) {
      const int k1 = (step + 1) * BK;
#pragma unroll
      for (int r = 0; r < 8; ++r) {
        ra[r] = *(const float4*)(gA + (size_t)r * (32 * EMB) + k1);
        rb[r] = *(const float4*)(gB + (size_t)r * (32 * EMB) + k1);
      }
    }

    // compute current tile: sim += ctxTile * entTile^T
#pragma unroll
    for (int kh = 0; kh < 2; ++kh) {
      const int kq = kh * 32 + qw * 8;
      bf16x8 a0 = __builtin_bit_cast(bf16x8, *(const short8*)&lsA[cur][lt0 * 16 + lr][kq]);
      bf16x8 a1 = __builtin_bit_cast(bf16x8, *(const short8*)&lsA[cur][lt1 * 16 + lr][kq]);
#pragma unroll
      for (int mt = 0; mt < 16; ++mt) {
        bf16x8 bfr = __builtin_bit_cast(bf16x8, *(const short8*)&lsB[cur][mt * 16 + lr][kq]);
        acc[0][mt] = __builtin_amdgcn_mfma_f32_16x16x32_bf16(a0, bfr, acc[0][mt], 0, 0, 0);
        acc[1][mt] = __builtin_amdgcn_mfma_f32_16x16x32_bf16(a1, bfr, acc[1][mt], 0, 0, 0);
      }
    }

    // convert + commit next tile to the other buffer
    if (step + 1 < NSTEP) {
#pragma unroll
      for (int r = 0; r < 8; ++r) {
        const int row = r * 32 + srow;
        *(uint2*)&lsA[cur ^ 1][row][scol] = pack4bf(ra[r]);
        *(uint2*)&lsB[cur ^ 1][row][scol] = pack4bf(rb[r]);
      }
    }
    __syncthreads();
  }

  // ---- epilogue: rowmax over m (256 cols), then sum over rows ----
  // C/D layout (16x16x32): col = lane&15, row = (lane>>4)*4 + reg
  float s = 0.f;
#pragma unroll
  for (int h = 0; h < 2; ++h) {
#pragma unroll
    for (int i = 0; i < 4; ++i) {
      float m = acc[h][0][i];
#pragma unroll
      for (int mt = 1; mt < 16; ++mt) m = fmaxf(m, acc[h][mt][i]);
      // max across the 16 lanes holding different cols of the same row
#pragma unroll
      for (int d = 1; d < 16; d <<= 1) m = fmaxf(m, __shfl_xor(m, d, 64));
      s += m;
    }
  }
  // groups of 16 lanes hold disjoint row-sets; lanes within a group are identical
  s += __shfl_xor(s, 16, 64);
  s += __shfl_xor(s, 32, 64);

  if (lane == 0) red[w] = s;
  __syncthreads();
  if (t == 0) {
    float tot = 0.f;
#pragma unroll
    for (int i = 0; i < 8; ++i) tot += red[i];
    out[p] = tot;
  }
}

extern "C" void kernel_launch(void* const* d_in, const int* in_sizes, int n_in,
                              void* d_out, int out_size, void* d_ws, size_t ws_size,
                              hipStream_t stream) {
  const float* ctx_all = (const float*)d_in[0];
  float* out = (float*)d_out;
  som_rowmax_kernel<<<dim3(512), dim3(512), 0, stream>>>(ctx_all, out);
}

// Round 2
// 150.586 us; speedup vs baseline: 1.0578x; 1.0578x over previous
//
#include <hip/hip_runtime.h>

// out[b,k] = sum_l max_m dot(ctx[b,k,l,:], ent[b,k,m,:])
// ctx = context[:,:,0,:,:], ent = context[:,:,1,:,:]
// BATCH=8 TOP_K=64 MAX_LEN=256 EMB_DIM=768, fp32 in, fp32 out (8x64=512)
//
// R2: A (ctx) loads go global->reg->bf16 frags per wave (no LDS for A).
//     B (ent) LDS double-buffered, but staged via regs with a software
//     pipeline that keeps 16 global loads in flight ACROSS each barrier:
//     raw s_barrier + lgkmcnt(0) only (no vmcnt drain).

#define MAXLEN 256
#define EMB 768
#define BK 64
#define NSTEP 12
#define LSTRIDE 72  // 64 + 8 pad shorts -> 144 B row stride

typedef __attribute__((ext_vector_type(4))) float f32x4;
typedef __attribute__((ext_vector_type(8))) short short8;
typedef __bf16 bf16x8 __attribute__((ext_vector_type(8)));

// round-to-nearest-even f32 -> bf16, packed pair (a -> low 16, b -> high 16)
__device__ inline unsigned int pack2bf(float a, float b) {
  unsigned int ua = __builtin_bit_cast(unsigned int, a);
  unsigned int ub = __builtin_bit_cast(unsigned int, b);
  ua = (ua + (0x7fffu + ((ua >> 16) & 1u))) >> 16;
  ub = (ub + (0x7fffu + ((ub >> 16) & 1u))) & 0xffff0000u;
  return ua | ub;
}

__device__ inline uint2 pack4bf(float4 v) {
  uint2 r;
  r.x = pack2bf(v.x, v.y);
  r.y = pack2bf(v.z, v.w);
  return r;
}

__device__ inline bf16x8 pack8bf(float4 a, float4 b) {
  union { unsigned int u[4]; bf16x8 v; } r;
  r.u[0] = pack2bf(a.x, a.y);
  r.u[1] = pack2bf(a.z, a.w);
  r.u[2] = pack2bf(b.x, b.y);
  r.u[3] = pack2bf(b.z, b.w);
  return r.v;
}

__global__ __launch_bounds__(512, 2) void som_rowmax_kernel(
    const float* __restrict__ ctx_all, float* __restrict__ out) {
  __shared__ __align__(16) short lsB[2][MAXLEN][LSTRIDE];
  __shared__ float red[8];

  const int t    = threadIdx.x;
  const int w    = t >> 6;      // wave 0..7
  const int lane = t & 63;
  const int qw   = lane >> 4;   // quarter-wave 0..3
  const int lr   = lane & 15;

  const size_t p = blockIdx.x;  // b*64 + k
  const float* ctx = ctx_all + p * (size_t)(2 * MAXLEN * EMB);
  const float* ent = ctx + (size_t)(MAXLEN * EMB);

  // B staging geometry: 8 rounds x (32 rows x 16 float4-cols) covers 256x64
  const int srow = t >> 4;         // 0..31
  const int scol = (t & 15) * 4;   // 0,4,...,60
  const float* gB = ent + (size_t)srow * EMB + scol;

  // A fragment geometry: wave w owns tile-rows 2w, 2w+1 (A rows 32w..32w+31)
  const int lt0 = 2 * w, lt1 = 2 * w + 1;
  const float* gA0 = ctx + (size_t)(lt0 * 16 + lr) * EMB + qw * 8;
  const float* gA1 = ctx + (size_t)(lt1 * 16 + lr) * EMB + qw * 8;

  f32x4 acc[2][16];
#pragma unroll
  for (int h = 0; h < 2; ++h)
#pragma unroll
    for (int mt = 0; mt < 16; ++mt)
      acc[h][mt] = (f32x4){0.f, 0.f, 0.f, 0.f};

  float4 rb[8];        // B(s+1) in flight
  float4 raA[8];       // A(s+1) in flight: [tile*4 + kh*2 + half]
  bf16x8 afr[2][2];    // A(s) fragments, ready for MFMA

  auto issueB = [&](int s) {
#pragma unroll
    for (int r = 0; r < 8; ++r)
      rb[r] = *(const float4*)(gB + (size_t)r * (32 * EMB) + s * BK);
  };
  auto commitB = [&](int buf) {
#pragma unroll
    for (int r = 0; r < 8; ++r) {
      const int row = r * 32 + srow;
      *(uint2*)&lsB[buf][row][scol] = pack4bf(rb[r]);
    }
  };
  auto issueA = [&](int s) {
#pragma unroll
    for (int kh = 0; kh < 2; ++kh)
#pragma unroll
      for (int half = 0; half < 2; ++half) {
        raA[0 * 4 + kh * 2 + half] = *(const float4*)(gA0 + s * BK + kh * 32 + half * 4);
        raA[1 * 4 + kh * 2 + half] = *(const float4*)(gA1 + s * BK + kh * 32 + half * 4);
      }
  };
  auto packA = [&]() {
#pragma unroll
    for (int tile = 0; tile < 2; ++tile)
#pragma unroll
      for (int kh = 0; kh < 2; ++kh)
        afr[tile][kh] = pack8bf(raA[tile * 4 + kh * 2 + 0], raA[tile * 4 + kh * 2 + 1]);
  };
  auto mfmaStep = [&](int buf) {
#pragma unroll
    for (int kh = 0; kh < 2; ++kh) {
      const int kq = kh * 32 + qw * 8;
#pragma unroll
      for (int mt = 0; mt < 16; ++mt) {
        bf16x8 bfr = __builtin_bit_cast(bf16x8, *(const short8*)&lsB[buf][mt * 16 + lr][kq]);
        acc[0][mt] = __builtin_amdgcn_mfma_f32_16x16x32_bf16(afr[0][kh], bfr, acc[0][mt], 0, 0, 0);
        acc[1][mt] = __builtin_amdgcn_mfma_f32_16x16x32_bf16(afr[1][kh], bfr, acc[1][mt], 0, 0, 0);
      }
    }
  };
  // barrier that does NOT drain vmcnt: global loads stay in flight across it
  auto barrier = [&]() {
    asm volatile("s_waitcnt lgkmcnt(0)" ::: "memory");
    __builtin_amdgcn_sched_barrier(0);
    __builtin_amdgcn_s_barrier();
    __builtin_amdgcn_sched_barrier(0);
  };

  // ---- prologue ----
  issueB(0);        // oldest in flight
  issueA(0);
  commitB(0);       // waits rb (vmcnt(16): A0 stays outstanding)
  issueB(1);
  packA();          // waits raA (vmcnt(16): B1 stays outstanding)
  barrier();

  // ---- steady state: s = 0..9 (full pipeline) ----
  for (int s = 0; s < NSTEP - 2; ++s) {
    issueA(s + 1);            // newest
    commitB((s + 1) & 1);     // waits B(s+1) -> vmcnt keeps A(s+1) in flight
    issueB(s + 2);
    mfmaStep(s & 1);
    packA();                  // waits A(s+1) -> vmcnt keeps B(s+2) in flight
    barrier();                // B(s+2) still outstanding across the barrier
  }
  // ---- peel s = 10 ----
  issueA(NSTEP - 1);
  commitB((NSTEP - 1) & 1);
  mfmaStep((NSTEP - 2) & 1);
  packA();
  barrier();
  // ---- peel s = 11 ----
  mfmaStep((NSTEP - 1) & 1);

  // ---- epilogue: rowmax over m (256 cols), then sum over rows ----
  // C/D layout (16x16x32): col = lane&15, row = (lane>>4)*4 + reg
  float s = 0.f;
#pragma unroll
  for (int h = 0; h < 2; ++h) {
#pragma unroll
    for (int i = 0; i < 4; ++i) {
      float m = acc[h][0][i];
#pragma unroll
      for (int mt = 1; mt < 16; ++mt) m = fmaxf(m, acc[h][mt][i]);
#pragma unroll
      for (int d = 1; d < 16; d <<= 1) m = fmaxf(m, __shfl_xor(m, d, 64));
      s += m;
    }
  }
  s += __shfl_xor(s, 16, 64);
  s += __shfl_xor(s, 32, 64);

  if (lane == 0) red[w] = s;
  __syncthreads();
  if (t == 0) {
    float tot = 0.f;
#pragma unroll
    for (int i = 0; i < 8; ++i) tot += red[i];
    out[p] = tot;
  }
}

extern "C" void kernel_launch(void* const* d_in, const int* in_sizes, int n_in,
                              void* d_out, int out_size, void* d_ws, size_t ws_size,
                              hipStream_t stream) {
  const float* ctx_all = (const float*)d_in[0];
  float* out = (float*)d_out;
  som_rowmax_kernel<<<dim3(512), dim3(512), 0, stream>>>(ctx_all, out);
}